// Round 4
// baseline (127.242 us; speedup 1.0000x reference)
//
#include <hip/hip_runtime.h>
#include <cstdint>
#include <cstddef>

// out[64,197,768] = concat(cls, patchify(images[64,3,224,224]) @ W^T + b)
// R4: software-pipelined K-loop. Double-buffered LDS stages for A and B;
// A(kt+1) global fp32 loads issued before compute(kt) (vmcnt wait covered by
// MFMA), cvt+ds_write after compute; B(kt+1) via global_load_lds into the
// alternate stage, drained by the end-of-iter barrier after being in flight
// for the whole compute phase.
#define MTOT 12544   // 64*196
#define KTOT 768

typedef float  f32x4  __attribute__((ext_vector_type(4)));
typedef __bf16 bf16x8 __attribute__((ext_vector_type(8)));

// ---------------- Prep: W fp32->bf16 + cls rows (tiny) ----------------
#define W_BLOCKS   288   // 768*768/8/256
#define CLS_BLOCKS 48    // 64*768/4/256

__global__ __launch_bounds__(256) void prep_kernel(
    const float* __restrict__ Wm, const float* __restrict__ cls,
    float* __restrict__ out, __bf16* __restrict__ Wb) {
  const int bid = blockIdx.x, tid = threadIdx.x;
  if (bid < W_BLOCKS) {
    const size_t q = (size_t)bid * 256 + tid;
    const float4 v0 = *(const float4*)(Wm + q * 8);
    const float4 v1 = *(const float4*)(Wm + q * 8 + 4);
    bf16x8 o;
    o[0]=(__bf16)v0.x; o[1]=(__bf16)v0.y; o[2]=(__bf16)v0.z; o[3]=(__bf16)v0.w;
    o[4]=(__bf16)v1.x; o[5]=(__bf16)v1.y; o[6]=(__bf16)v1.z; o[7]=(__bf16)v1.w;
    *(bf16x8*)(Wb + q * 8) = o;
  } else {
    const int t  = (bid - W_BLOCKS) * 256 + tid;
    const int bb = t / 192;
    const int r  = t - bb * 192;
    *(float4*)(out + (size_t)bb * 197 * 768 + r * 4) = *(const float4*)(cls + r * 4);
  }
}

// ---------------- GEMM: fused patchify + pipelined MFMA ----------------
#define BM 64
#define BN 128
#define APAD 40                 // 80B rows: odd 16B-group stride, conflict-min
#define NBLK_N 6
#define ASTAGE (2 * BM * APAD)  // 5120 elems / stage (10.25 KB)
#define BSTAGE (2 * BN * 32)    // 8192 elems / stage (16 KB)

__device__ __forceinline__ void gload_lds16(const void* g, void* l) {
  __builtin_amdgcn_global_load_lds((__attribute__((address_space(1))) void*)(g),
                                   (__attribute__((address_space(3))) void*)(l),
                                   16, 0, 0);
}

__device__ __forceinline__ void cvt_store(__bf16* dst, const f32x4 a, const f32x4 b) {
  bf16x8 o;
  o[0]=(__bf16)a[0]; o[1]=(__bf16)a[1]; o[2]=(__bf16)a[2]; o[3]=(__bf16)a[3];
  o[4]=(__bf16)b[0]; o[5]=(__bf16)b[1]; o[6]=(__bf16)b[2]; o[7]=(__bf16)b[3];
  *(bf16x8*)dst = o;
}

__global__ __launch_bounds__(256, 3) void gemm_kernel(
    const float* __restrict__ images, const __bf16* __restrict__ Wb,
    const float* __restrict__ bias, float* __restrict__ out) {
  __shared__ __bf16 As[2 * ASTAGE];  // 20.5 KB
  __shared__ __bf16 Bs[2 * BSTAGE];  // 32 KB

  const int tid = threadIdx.x;
  // XCD swizzle: contiguous tile slices per XCD for image-L2 locality.
  const int g    = (blockIdx.x & 7) * 147 + (blockIdx.x >> 3);
  const int mblk = g / NBLK_N, nblk = g - mblk * NBLK_N;
  const int m0 = mblk * BM, n0 = nblk * BN;
  const int wave = tid >> 6, lane = tid & 63;
  const int wm = (wave & 1) * 32, wn = (wave >> 1) * 64;
  const int lrow = lane & 15, lq = lane >> 4;

  // A gather: thread owns (row=lane, 16-k seg = wave) -> one 64B fp32 image
  // row segment per tile.
  const int row = lane;
  const int m  = m0 + row;
  const int bb = m / 196, p = m - bb * 196;
  const int pi = p / 14,  pj = p - pi * 14;
  const float* gA = images +
      ((size_t)(bb * 3) * 224 + (size_t)(pi * 16 + wave)) * 224 + pj * 16;
  const int aoff = ((wave >> 1) * BM + row) * APAD + (wave & 1) * 16;

  // B staging: 1024 chunks of 16B per tile, 4/thread, wave-uniform LDS base.
  const __bf16* pB[4];
  int lBoff[4];
#pragma unroll
  for (int s = 0; s < 4; ++s) {
    const int c  = wave * 256 + s * 64 + lane;
    const int ks = c >> 9, rem = c & 511, h = rem >> 2, jc = rem & 3;
    pB[s] = Wb + (size_t)(n0 + h) * 768 + ks * 32 + jc * 8;
    lBoff[s] = (wave * 256 + s * 64) * 8;
  }

  // ---- Prologue: stage tile 0 into stage 0 ----
  {
    const f32x4 v0 = *(const f32x4*)(gA);
    const f32x4 v1 = *(const f32x4*)(gA + 4);
    const f32x4 v2 = *(const f32x4*)(gA + 8);
    const f32x4 v3 = *(const f32x4*)(gA + 12);
#pragma unroll
    for (int s = 0; s < 4; ++s) gload_lds16(pB[s], Bs + lBoff[s]);
#pragma unroll
    for (int s = 0; s < 4; ++s) pB[s] += 64;
    gA += 896;  // tile 0 -> 1 advance (d(0))
    cvt_store(&As[aoff],     v0, v1);
    cvt_store(&As[aoff + 8], v2, v3);
  }
  __syncthreads();

  f32x4 acc[2][4] = {};

  for (int kt = 0; kt < 12; ++kt) {
    const int cur = kt & 1, nxt = cur ^ 1;
    f32x4 u0, u1, u2, u3;
    if (kt < 11) {
      // A(kt+1) -> VGPRs (issued FIRST so its vmcnt wait doesn't drain B's DMA)
      u0 = *(const f32x4*)(gA);
      u1 = *(const f32x4*)(gA + 4);
      u2 = *(const f32x4*)(gA + 8);
      u3 = *(const f32x4*)(gA + 12);
      // B(kt+1) -> alternate LDS stage via DMA
#pragma unroll
      for (int s = 0; s < 4; ++s) gload_lds16(pB[s], Bs + nxt * BSTAGE + lBoff[s]);
#pragma unroll
      for (int s = 0; s < 4; ++s) pB[s] += 64;
      gA += (((kt + 1) & 3) == 3) ? 47488 : 896;  // advance past tile kt+1
    }

    // ---- compute tile kt from stage cur ----
#pragma unroll
    for (int ks = 0; ks < 2; ++ks) {
      bf16x8 af[2], bf[4];
#pragma unroll
      for (int i = 0; i < 2; ++i)
        af[i] = *(const bf16x8*)&As[cur * ASTAGE + (ks * BM + wm + i * 16 + lrow) * APAD + lq * 8];
#pragma unroll
      for (int j = 0; j < 4; ++j)
        bf[j] = *(const bf16x8*)&Bs[cur * BSTAGE + (ks * BN + wn + j * 16 + lrow) * 32 + lq * 8];
#pragma unroll
      for (int i = 0; i < 2; ++i)
#pragma unroll
        for (int j = 0; j < 4; ++j)
          acc[i][j] = __builtin_amdgcn_mfma_f32_16x16x32_bf16(af[i], bf[j], acc[i][j], 0, 0, 0);
    }

    if (kt < 11) {
      // cvt+write A(kt+1) (vmcnt wait here, covered by the MFMA block above)
      cvt_store(&As[nxt * ASTAGE + aoff],     u0, u1);
      cvt_store(&As[nxt * ASTAGE + aoff + 8], u2, u3);
      __syncthreads();  // drains B DMA (in flight all compute) + A ds_writes
    }
  }

  // Epilogue: C/D layout col=lane&15, row=(lane>>4)*4+r; scatter past cls.
#pragma unroll
  for (int j = 0; j < 4; ++j) {
    const int h  = n0 + wn + j * 16 + lrow;
    const float bv = bias[h];
#pragma unroll
    for (int i = 0; i < 2; ++i) {
      const int mb = m0 + wm + i * 16 + lq * 4;
#pragma unroll
      for (int r = 0; r < 4; ++r) {
        const int mm  = mb + r;
        const int bb2 = mm / 196, p2 = mm - bb2 * 196;
        out[(size_t)(bb2 * 197 + 1 + p2) * 768 + h] = acc[i][j][r] + bv;
      }
    }
  }
}

extern "C" void kernel_launch(void* const* d_in, const int* in_sizes, int n_in,
                              void* d_out, int out_size, void* d_ws, size_t ws_size,
                              hipStream_t stream) {
  const float* images = (const float*)d_in[0];  // [64,3,224,224]
  const float* Wm     = (const float*)d_in[1];  // [768,768]
  const float* b      = (const float*)d_in[2];  // [768]
  const float* cls    = (const float*)d_in[3];  // [1,768]
  float* out = (float*)d_out;                   // [64,197,768]
  __bf16* Wb = (__bf16*)d_ws;                   // 1.18 MB
  (void)in_sizes; (void)n_in; (void)out_size; (void)ws_size;

  prep_kernel<<<W_BLOCKS + CLS_BLOCKS, 256, 0, stream>>>(Wm, cls, out, Wb);
  gemm_kernel<<<(MTOT / BM) * NBLK_N, 256, 0, stream>>>(images, Wb, b, out);
}